// Round 3
// baseline (219.994 us; speedup 1.0000x reference)
//
#include <hip/hip_runtime.h>
#include <hip/hip_bf16.h>
#include <math.h>

// Problem constants
#define LH 4      // left heads
#define RH 4      // right heads
#define HD 16     // per-head hidden
#define DD 64     // L*H = R*H = 64
#define BB 2
#define TT 96
#define NTOK (BB*TT)           // 192
#define HEADS (LH*RH)          // 16
#define INV_H 0.0625f
#define NQ 2                   // queries per block (per thread)
#define QCHUNKS (TT/NQ)        // 48
#define CS 4                   // column-split blocks per token (16 cols each)
#define CB 16                  // columns per block

// ---------------------------------------------------------------------------
// PartialDense body: computes Y[:, c0:c0+16] = (Wr^T (X Wc) + b)[:, c0:c0+16] * scale
// for one token. X staged transposed in LDS; weights streamed from global (L1).
// ---------------------------------------------------------------------------
__device__ __forceinline__ void pdense_body(
    const float* __restrict__ Xp,   // this token's 64x64 input
    const float* __restrict__ Wr, const float* __restrict__ Wc,
    const float* __restrict__ bias, float* __restrict__ dst,
    float scale, int separated, int token, int rblk /* = c0/16 */)
{
    __shared__ float XsT[64][68];      // transposed, padded (float4-aligned rows)
    __shared__ float T1s[64][17];      // T1[:, c0:c0+16], padded

    const int tid = threadIdx.x;
    const int c0 = rblk * CB;
    const int c  = tid & 15;
    const int g4 = tid >> 4;           // 0..15
    const int a0 = g4 * 4;

    // stage X transposed: XsT[j][i] = X[i][j]
    #pragma unroll
    for (int rep = 0; rep < 16; ++rep) {
        int idx = tid + rep * 256;
        int i = idx >> 6, j = idx & 63;
        XsT[j][i] = Xp[idx];
    }
    __syncthreads();

    // pass 1: T1[i][c] = sum_j X[i][j] * Wc[j][c0+c], 4 i's per thread
    {
        const float4* XsT4 = (const float4*)&XsT[0][0];
        float4 s = {0.f, 0.f, 0.f, 0.f};
        #pragma unroll 8
        for (int j = 0; j < 64; ++j) {
            float4 xv = XsT4[j * 17 + g4];       // X[a0..a0+3][j]
            float  wc = Wc[j * 64 + c0 + c];
            s.x += xv.x * wc; s.y += xv.y * wc;
            s.z += xv.z * wc; s.w += xv.w * wc;
        }
        T1s[a0 + 0][c] = s.x; T1s[a0 + 1][c] = s.y;
        T1s[a0 + 2][c] = s.z; T1s[a0 + 3][c] = s.w;
    }
    __syncthreads();

    // pass 2: Y[a][c0+c] = sum_ii Wr[ii][a] * T1[ii][c], 4 a's per thread
    {
        const float4* Wr4 = (const float4*)Wr;
        float4 s = {0.f, 0.f, 0.f, 0.f};
        #pragma unroll 8
        for (int ii = 0; ii < 64; ++ii) {
            float4 wv = Wr4[ii * 16 + g4];       // Wr[ii][a0..a0+3]
            float  t  = T1s[ii][c];
            s.x += wv.x * t; s.y += wv.y * t;
            s.z += wv.z * t; s.w += wv.w * t;
        }
        float y[4] = {s.x, s.y, s.z, s.w};
        if (separated) {
            const int bI = token / TT, t = token % TT;
            #pragma unroll
            for (int q = 0; q < 4; ++q) {
                int a = a0 + q, l = a >> 4, p = a & 15;
                float v = (y[q] + bias[a * 64 + c0 + c]) * scale;
                dst[(((bI * HEADS + (l * RH + rblk)) * TT) + t) * 256 + p * 16 + c] = v;
            }
        } else {
            #pragma unroll
            for (int q = 0; q < 4; ++q) {
                int a = a0 + q;
                float v = (y[q] + bias[a * 64 + c0 + c]) * scale;
                dst[token * 4096 + a * 64 + c0 + c] = v;
            }
        }
    }
}

// Fused q/k/v projection: blockIdx -> (which in {q,k,v}, token, rblk)
__global__ __launch_bounds__(256) void pdense_qkv_kernel(
    const float* __restrict__ Xq, const float* __restrict__ Xk, const float* __restrict__ Xv,
    const float* __restrict__ Wq_row, const float* __restrict__ Wq_col, const float* __restrict__ bq,
    const float* __restrict__ Wk_row, const float* __restrict__ Wk_col, const float* __restrict__ bk,
    const float* __restrict__ Wv_row, const float* __restrict__ Wv_col, const float* __restrict__ bv,
    float* __restrict__ q_s, float* __restrict__ k_s, float* __restrict__ v_s)
{
    const int per = NTOK * CS;                  // 768 blocks per input
    const int which = blockIdx.x / per;
    const int rem   = blockIdx.x % per;
    const int token = rem / CS;
    const int rblk  = rem % CS;

    if (which == 0)
        pdense_body(Xq + token * 4096, Wq_row, Wq_col, bq, q_s, INV_H, 1, token, rblk);
    else if (which == 1)
        pdense_body(Xk + token * 4096, Wk_row, Wk_col, bk, k_s, INV_H, 1, token, rblk);
    else
        pdense_body(Xv + token * 4096, Wv_row, Wv_col, bv, v_s, INV_H, 1, token, rblk);
}

// Output projection
__global__ __launch_bounds__(256) void pdense_out_kernel(
    const float* __restrict__ X, const float* __restrict__ Wr,
    const float* __restrict__ Wc, const float* __restrict__ bias,
    float* __restrict__ dst)
{
    const int token = blockIdx.x / CS;
    const int rblk  = blockIdx.x % CS;
    pdense_body(X + token * 4096, Wr, Wc, bias, dst, INV_H, 0, token, rblk);
}

// ---------------------------------------------------------------------------
// Fused attention. Block = (batch, head, chunk of NQ query tokens).
// Thread (p,u) owns softmax rows (i0..i0+NQ-1, p, u) over j.
// No max subtraction: logits are tiny (|S| << 1), exp(S) is safe in fp32.
// r > l blocks write zeros (the causal head-grid mask).
// ---------------------------------------------------------------------------
__global__ __launch_bounds__(256, 2) void attn_kernel(
    const float* __restrict__ q_s, const float* __restrict__ k_s,
    const float* __restrict__ v_s, float* __restrict__ att)
{
    const int qc   = blockIdx.x % QCHUNKS;
    const int head = (blockIdx.x / QCHUNKS) % HEADS;
    const int bI   = blockIdx.x / (QCHUNKS * HEADS);
    const int l = head >> 2, r = head & 3;
    const int i0 = qc * NQ;
    const int tid = threadIdx.x;
    const int p = tid >> 4, u = tid & 15;

    if (r > l) {
        #pragma unroll
        for (int qi = 0; qi < NQ; ++qi)
            att[(((size_t)(bI * TT + i0 + qi) * DD) + (l * 16 + p)) * DD + r * 16 + u] = 0.f;
        return;
    }

    const size_t hb = (size_t)(bI * HEADS + head) * TT * 256;

    // Q rows (p,:) for NQ query tokens
    float4 q[NQ][4];
    #pragma unroll
    for (int qi = 0; qi < NQ; ++qi) {
        const float4* qp = (const float4*)(q_s + hb + (size_t)(i0 + qi) * 256 + p * 16);
        q[qi][0] = qp[0]; q[qi][1] = qp[1]; q[qi][2] = qp[2]; q[qi][3] = qp[3];
    }

    const float* kb = k_s + hb + u * 16;
    const float* vb = v_s + hb + u * 16;

    float lsum[NQ];
    float acc[NQ][16];
    #pragma unroll
    for (int qi = 0; qi < NQ; ++qi) {
        lsum[qi] = 0.f;
        #pragma unroll
        for (int t = 0; t < 16; ++t) acc[qi][t] = 0.f;
    }

    #pragma unroll 2
    for (int j = 0; j < TT; ++j) {
        const float4* kr = (const float4*)(kb + (size_t)j * 256);
        float4 k0 = kr[0], k1 = kr[1], k2 = kr[2], k3 = kr[3];
        const float4* vr = (const float4*)(vb + (size_t)j * 256);
        float4 v0 = vr[0], v1 = vr[1], v2 = vr[2], v3 = vr[3];

        #pragma unroll
        for (int qi = 0; qi < NQ; ++qi) {
            float S =
                q[qi][0].x*k0.x + q[qi][0].y*k0.y + q[qi][0].z*k0.z + q[qi][0].w*k0.w +
                q[qi][1].x*k1.x + q[qi][1].y*k1.y + q[qi][1].z*k1.z + q[qi][1].w*k1.w +
                q[qi][2].x*k2.x + q[qi][2].y*k2.y + q[qi][2].z*k2.z + q[qi][2].w*k2.w +
                q[qi][3].x*k3.x + q[qi][3].y*k3.y + q[qi][3].z*k3.z + q[qi][3].w*k3.w;
            float w = __expf(S * INV_H);
            lsum[qi] += w;
            acc[qi][0]  += w * v0.x;  acc[qi][1]  += w * v0.y;
            acc[qi][2]  += w * v0.z;  acc[qi][3]  += w * v0.w;
            acc[qi][4]  += w * v1.x;  acc[qi][5]  += w * v1.y;
            acc[qi][6]  += w * v1.z;  acc[qi][7]  += w * v1.w;
            acc[qi][8]  += w * v2.x;  acc[qi][9]  += w * v2.y;
            acc[qi][10] += w * v2.z;  acc[qi][11] += w * v2.w;
            acc[qi][12] += w * v3.x;  acc[qi][13] += w * v3.y;
            acc[qi][14] += w * v3.z;  acc[qi][15] += w * v3.w;
        }
    }

    #pragma unroll
    for (int qi = 0; qi < NQ; ++qi) {
        float inv = 1.f / lsum[qi];
        #pragma unroll
        for (int t = 0; t < 16; ++t) acc[qi][t] *= inv;

        // reduce over u (16-lane groups)
        #pragma unroll
        for (int mask = 1; mask < 16; mask <<= 1) {
            #pragma unroll
            for (int t = 0; t < 16; ++t)
                acc[qi][t] += __shfl_xor(acc[qi][t], mask, 16);
        }

        // lane u keeps output column u; static-index select (avoid scratch)
        float outv = acc[qi][0];
        #pragma unroll
        for (int t = 1; t < 16; ++t)
            outv = (u == t) ? acc[qi][t] : outv;

        att[(((size_t)(bI * TT + i0 + qi) * DD) + (l * 16 + p)) * DD + r * 16 + u] = outv;
    }
}

// ---------------------------------------------------------------------------
extern "C" void kernel_launch(void* const* d_in, const int* in_sizes, int n_in,
                              void* d_out, int out_size, void* d_ws, size_t ws_size,
                              hipStream_t stream) {
    const float* queries = (const float*)d_in[0];
    const float* keys    = (const float*)d_in[1];
    const float* values  = (const float*)d_in[2];
    const float* Wq_row  = (const float*)d_in[3];
    const float* Wq_col  = (const float*)d_in[4];
    const float* bq      = (const float*)d_in[5];
    const float* Wk_row  = (const float*)d_in[6];
    const float* Wk_col  = (const float*)d_in[7];
    const float* bk      = (const float*)d_in[8];
    const float* Wv_row  = (const float*)d_in[9];
    const float* Wv_col  = (const float*)d_in[10];
    const float* bv      = (const float*)d_in[11];
    const float* Wo_row  = (const float*)d_in[12];
    const float* Wo_col  = (const float*)d_in[13];
    const float* bo      = (const float*)d_in[14];
    float* out = (float*)d_out;

    const size_t SEP = (size_t)BB * HEADS * TT * 256;  // 786432 floats
    float* ws  = (float*)d_ws;
    float* q_s = ws;
    float* k_s = q_s + SEP;
    float* v_s = k_s + SEP;
    float* att = v_s + SEP;

    pdense_qkv_kernel<<<3 * NTOK * CS, 256, 0, stream>>>(
        queries, keys, values,
        Wq_row, Wq_col, bq, Wk_row, Wk_col, bk, Wv_row, Wv_col, bv,
        q_s, k_s, v_s);

    attn_kernel<<<BB * HEADS * QCHUNKS, 256, 0, stream>>>(q_s, k_s, v_s, att);

    pdense_out_kernel<<<NTOK * CS, 256, 0, stream>>>(att, Wo_row, Wo_col, bo, out);
}

// Round 4
// 110.362 us; speedup vs baseline: 1.9934x; 1.9934x over previous
//
#include <hip/hip_runtime.h>
#include <hip/hip_bf16.h>
#include <math.h>

// Problem constants
#define LH 4      // left heads
#define RH 4      // right heads
#define HD 16     // per-head hidden
#define DD 64     // L*H = R*H = 64
#define BB 2
#define TT 96
#define NTOK (BB*TT)           // 192
#define HEADS (LH*RH)          // 16
#define INV_H 0.0625f
#define NQ 2                   // queries per block (per thread)
#define QCHUNKS (TT/NQ)        // 48
#define CS 4                   // pdense column-split blocks per token
#define CB 16                  // columns per pdense block
#define JC 16                  // K/V j-chunk staged in LDS
#define NCHUNK (TT/JC)         // 6
#define KSTRIDE 260            // padded LDS row stride (dwords) per u
#define KSTRIDE4 65            // in float4s

// ---------------------------------------------------------------------------
// PartialDense body: Y[:, c0:c0+16] = (Wr^T (X Wc) + b)[:, c0:c0+16] * scale
// ---------------------------------------------------------------------------
__device__ __forceinline__ void pdense_body(
    const float* __restrict__ Xp,
    const float* __restrict__ Wr, const float* __restrict__ Wc,
    const float* __restrict__ bias, float* __restrict__ dst,
    float scale, int separated, int token, int rblk)
{
    __shared__ float XsT[64][68];
    __shared__ float T1s[64][17];

    const int tid = threadIdx.x;
    const int c0 = rblk * CB;
    const int c  = tid & 15;
    const int g4 = tid >> 4;
    const int a0 = g4 * 4;

    #pragma unroll
    for (int rep = 0; rep < 16; ++rep) {
        int idx = tid + rep * 256;
        int i = idx >> 6, j = idx & 63;
        XsT[j][i] = Xp[idx];
    }
    __syncthreads();

    {
        const float4* XsT4 = (const float4*)&XsT[0][0];
        float4 s = {0.f, 0.f, 0.f, 0.f};
        #pragma unroll 8
        for (int j = 0; j < 64; ++j) {
            float4 xv = XsT4[j * 17 + g4];
            float  wc = Wc[j * 64 + c0 + c];
            s.x += xv.x * wc; s.y += xv.y * wc;
            s.z += xv.z * wc; s.w += xv.w * wc;
        }
        T1s[a0 + 0][c] = s.x; T1s[a0 + 1][c] = s.y;
        T1s[a0 + 2][c] = s.z; T1s[a0 + 3][c] = s.w;
    }
    __syncthreads();

    {
        const float4* Wr4 = (const float4*)Wr;
        float4 s = {0.f, 0.f, 0.f, 0.f};
        #pragma unroll 8
        for (int ii = 0; ii < 64; ++ii) {
            float4 wv = Wr4[ii * 16 + g4];
            float  t  = T1s[ii][c];
            s.x += wv.x * t; s.y += wv.y * t;
            s.z += wv.z * t; s.w += wv.w * t;
        }
        float y[4] = {s.x, s.y, s.z, s.w};
        if (separated) {
            const int bI = token / TT, t = token % TT;
            #pragma unroll
            for (int q = 0; q < 4; ++q) {
                int a = a0 + q, l = a >> 4, p = a & 15;
                float v = (y[q] + bias[a * 64 + c0 + c]) * scale;
                dst[(((bI * HEADS + (l * RH + rblk)) * TT) + t) * 256 + p * 16 + c] = v;
            }
        } else {
            #pragma unroll
            for (int q = 0; q < 4; ++q) {
                int a = a0 + q;
                float v = (y[q] + bias[a * 64 + c0 + c]) * scale;
                dst[token * 4096 + a * 64 + c0 + c] = v;
            }
        }
    }
}

__global__ __launch_bounds__(256) void pdense_qkv_kernel(
    const float* __restrict__ Xq, const float* __restrict__ Xk, const float* __restrict__ Xv,
    const float* __restrict__ Wq_row, const float* __restrict__ Wq_col, const float* __restrict__ bq,
    const float* __restrict__ Wk_row, const float* __restrict__ Wk_col, const float* __restrict__ bk,
    const float* __restrict__ Wv_row, const float* __restrict__ Wv_col, const float* __restrict__ bv,
    float* __restrict__ q_s, float* __restrict__ k_s, float* __restrict__ v_s)
{
    const int per = NTOK * CS;
    const int which = blockIdx.x / per;
    const int rem   = blockIdx.x % per;
    const int token = rem / CS;
    const int rblk  = rem % CS;

    if (which == 0)
        pdense_body(Xq + token * 4096, Wq_row, Wq_col, bq, q_s, INV_H, 1, token, rblk);
    else if (which == 1)
        pdense_body(Xk + token * 4096, Wk_row, Wk_col, bk, k_s, INV_H, 1, token, rblk);
    else
        pdense_body(Xv + token * 4096, Wv_row, Wv_col, bv, v_s, INV_H, 1, token, rblk);
}

__global__ __launch_bounds__(256) void pdense_out_kernel(
    const float* __restrict__ X, const float* __restrict__ Wr,
    const float* __restrict__ Wc, const float* __restrict__ bias,
    float* __restrict__ dst)
{
    const int token = blockIdx.x / CS;
    const int rblk  = blockIdx.x % CS;
    pdense_body(X + token * 4096, Wr, Wc, bias, dst, INV_H, 0, token, rblk);
}

// ---------------------------------------------------------------------------
// Fused attention. Block = (batch, head, chunk of NQ query tokens).
// K/V staged in LDS per 16-j chunk, padded [u][260] layout (2-way conflicts max).
// Dot products computed as 4 chains of 4 FMAs + tree combine (short critical path).
// ---------------------------------------------------------------------------
__global__ __launch_bounds__(256, 2) void attn_kernel(
    const float* __restrict__ q_s, const float* __restrict__ k_s,
    const float* __restrict__ v_s, float* __restrict__ att)
{
    __shared__ float Ks[16 * KSTRIDE];
    __shared__ float Vs[16 * KSTRIDE];

    const int qc   = blockIdx.x % QCHUNKS;
    const int head = (blockIdx.x / QCHUNKS) % HEADS;
    const int bI   = blockIdx.x / (QCHUNKS * HEADS);
    const int l = head >> 2, r = head & 3;
    const int i0 = qc * NQ;
    const int tid = threadIdx.x;
    const int p = tid >> 4, u = tid & 15;

    if (r > l) {
        #pragma unroll
        for (int qi = 0; qi < NQ; ++qi)
            att[(((size_t)(bI * TT + i0 + qi) * DD) + (l * 16 + p)) * DD + r * 16 + u] = 0.f;
        return;
    }

    const size_t hb = (size_t)(bI * HEADS + head) * TT * 256;

    // Q rows (p,:) for NQ query tokens -> registers (stay resident, ~110 VGPR total)
    float4 q[NQ][4];
    #pragma unroll
    for (int qi = 0; qi < NQ; ++qi) {
        const float4* qp = (const float4*)(q_s + hb + (size_t)(i0 + qi) * 256 + p * 16);
        q[qi][0] = qp[0]; q[qi][1] = qp[1]; q[qi][2] = qp[2]; q[qi][3] = qp[3];
    }

    // staging indices: thread -> (jj = tid>>4, u = tid&15)
    const int su = tid & 15;
    const int sj = tid >> 4;
    float4* ksl = ((float4*)Ks) + su * KSTRIDE4 + sj * 4;
    float4* vsl = ((float4*)Vs) + su * KSTRIDE4 + sj * 4;

    float lsum[NQ];
    float acc[NQ][16];
    #pragma unroll
    for (int qi = 0; qi < NQ; ++qi) {
        lsum[qi] = 0.f;
        #pragma unroll
        for (int t = 0; t < 16; ++t) acc[qi][t] = 0.f;
    }

    const float4* kread = ((const float4*)Ks) + u * KSTRIDE4;
    const float4* vread = ((const float4*)Vs) + u * KSTRIDE4;

    for (int ch = 0; ch < NCHUNK; ++ch) {
        const int j0 = ch * JC;
        // stage K/V rows [j0 .. j0+15] into LDS
        {
            const float4* gk = (const float4*)(k_s + hb + (size_t)(j0 + sj) * 256 + su * 16);
            const float4* gv = (const float4*)(v_s + hb + (size_t)(j0 + sj) * 256 + su * 16);
            float4 a0 = gk[0], a1 = gk[1], a2 = gk[2], a3 = gk[3];
            float4 b0 = gv[0], b1 = gv[1], b2 = gv[2], b3 = gv[3];
            __syncthreads();   // protect previous chunk's readers
            ksl[0] = a0; ksl[1] = a1; ksl[2] = a2; ksl[3] = a3;
            vsl[0] = b0; vsl[1] = b1; vsl[2] = b2; vsl[3] = b3;
            __syncthreads();
        }

        #pragma unroll 4
        for (int jj = 0; jj < JC; ++jj) {
            float4 k0 = kread[jj * 4 + 0], k1 = kread[jj * 4 + 1];
            float4 k2 = kread[jj * 4 + 2], k3 = kread[jj * 4 + 3];
            float4 v0 = vread[jj * 4 + 0], v1 = vread[jj * 4 + 1];
            float4 v2 = vread[jj * 4 + 2], v3 = vread[jj * 4 + 3];

            #pragma unroll
            for (int qi = 0; qi < NQ; ++qi) {
                // 4 independent FMA chains + tree combine (short critical path)
                float g0 = q[qi][0].x * k0.x;
                g0 = fmaf(q[qi][0].y, k0.y, g0);
                g0 = fmaf(q[qi][0].z, k0.z, g0);
                g0 = fmaf(q[qi][0].w, k0.w, g0);
                float g1 = q[qi][1].x * k1.x;
                g1 = fmaf(q[qi][1].y, k1.y, g1);
                g1 = fmaf(q[qi][1].z, k1.z, g1);
                g1 = fmaf(q[qi][1].w, k1.w, g1);
                float g2 = q[qi][2].x * k2.x;
                g2 = fmaf(q[qi][2].y, k2.y, g2);
                g2 = fmaf(q[qi][2].z, k2.z, g2);
                g2 = fmaf(q[qi][2].w, k2.w, g2);
                float g3 = q[qi][3].x * k3.x;
                g3 = fmaf(q[qi][3].y, k3.y, g3);
                g3 = fmaf(q[qi][3].z, k3.z, g3);
                g3 = fmaf(q[qi][3].w, k3.w, g3);
                float S = (g0 + g1) + (g2 + g3);

                float w = __expf(S * INV_H);
                lsum[qi] += w;
                acc[qi][0]  += w * v0.x;  acc[qi][1]  += w * v0.y;
                acc[qi][2]  += w * v0.z;  acc[qi][3]  += w * v0.w;
                acc[qi][4]  += w * v1.x;  acc[qi][5]  += w * v1.y;
                acc[qi][6]  += w * v1.z;  acc[qi][7]  += w * v1.w;
                acc[qi][8]  += w * v2.x;  acc[qi][9]  += w * v2.y;
                acc[qi][10] += w * v2.z;  acc[qi][11] += w * v2.w;
                acc[qi][12] += w * v3.x;  acc[qi][13] += w * v3.y;
                acc[qi][14] += w * v3.z;  acc[qi][15] += w * v3.w;
            }
        }
    }

    #pragma unroll
    for (int qi = 0; qi < NQ; ++qi) {
        float inv = 1.f / lsum[qi];
        #pragma unroll
        for (int t = 0; t < 16; ++t) acc[qi][t] *= inv;

        #pragma unroll
        for (int mask = 1; mask < 16; mask <<= 1) {
            #pragma unroll
            for (int t = 0; t < 16; ++t)
                acc[qi][t] += __shfl_xor(acc[qi][t], mask, 16);
        }

        float outv = acc[qi][0];
        #pragma unroll
        for (int t = 1; t < 16; ++t)
            outv = (u == t) ? acc[qi][t] : outv;

        att[(((size_t)(bI * TT + i0 + qi) * DD) + (l * 16 + p)) * DD + r * 16 + u] = outv;
    }
}

// ---------------------------------------------------------------------------
extern "C" void kernel_launch(void* const* d_in, const int* in_sizes, int n_in,
                              void* d_out, int out_size, void* d_ws, size_t ws_size,
                              hipStream_t stream) {
    const float* queries = (const float*)d_in[0];
    const float* keys    = (const float*)d_in[1];
    const float* values  = (const float*)d_in[2];
    const float* Wq_row  = (const float*)d_in[3];
    const float* Wq_col  = (const float*)d_in[4];
    const float* bq      = (const float*)d_in[5];
    const float* Wk_row  = (const float*)d_in[6];
    const float* Wk_col  = (const float*)d_in[7];
    const float* bk      = (const float*)d_in[8];
    const float* Wv_row  = (const float*)d_in[9];
    const float* Wv_col  = (const float*)d_in[10];
    const float* bv      = (const float*)d_in[11];
    const float* Wo_row  = (const float*)d_in[12];
    const float* Wo_col  = (const float*)d_in[13];
    const float* bo      = (const float*)d_in[14];
    float* out = (float*)d_out;

    const size_t SEP = (size_t)BB * HEADS * TT * 256;
    float* ws  = (float*)d_ws;
    float* q_s = ws;
    float* k_s = q_s + SEP;
    float* v_s = k_s + SEP;
    float* att = v_s + SEP;

    pdense_qkv_kernel<<<3 * NTOK * CS, 256, 0, stream>>>(
        queries, keys, values,
        Wq_row, Wq_col, bq, Wk_row, Wk_col, bk, Wv_row, Wv_col, bv,
        q_s, k_s, v_s);

    attn_kernel<<<BB * HEADS * QCHUNKS, 256, 0, stream>>>(q_s, k_s, v_s, att);

    pdense_out_kernel<<<NTOK * CS, 256, 0, stream>>>(att, Wo_row, Wo_col, bo, out);
}

// Round 5
// 109.298 us; speedup vs baseline: 2.0128x; 1.0097x over previous
//
#include <hip/hip_runtime.h>
#include <hip/hip_bf16.h>
#include <math.h>

// Problem constants
#define LH 4      // left heads
#define RH 4      // right heads
#define HD 16     // per-head hidden
#define DD 64     // L*H = R*H = 64
#define BB 2
#define TT 96
#define NTOK (BB*TT)           // 192
#define HEADS (LH*RH)          // 16
#define INV_H 0.0625f
#define NQ 4                   // queries per block (per thread)
#define QCHUNKS (TT/NQ)        // 24
#define JC 16                  // K/V j-chunk staged in LDS
#define NCHUNK (TT/JC)         // 6
#define KSTRIDE 260            // padded LDS row stride (dwords) per u
#define KSTRIDE4 65            // in float4s

// ---------------------------------------------------------------------------
// PartialDense body: Y = (Wr^T (X Wc) + b) * scale for ONE token, all 64x64.
// Thread (g4 = i/a quad, cg = c quad) computes a 4x4 output tile per pass:
// 16 FMAs per 1 LDS float4 + 1 global float4 (L1-broadcast weights).
// ---------------------------------------------------------------------------
__device__ __forceinline__ void pdense_body(
    const float* __restrict__ Xp,
    const float* __restrict__ Wr, const float* __restrict__ Wc,
    const float* __restrict__ bias, float* __restrict__ dst,
    float scale, int separated, int token)
{
    __shared__ float XsT[64 * 68];   // X transposed: XsT[j*68 + i]
    __shared__ float T1r[64 * 68];   // T1 row-major: T1r[i*68 + c]

    const int tid = threadIdx.x;
    const int g4 = tid >> 4;         // 0..15 (i-quad / a-quad)
    const int cg = tid & 15;         // 0..15 (c-quad)

    // stage X transposed (coalesced global read, scalar LDS scatter)
    #pragma unroll
    for (int rep = 0; rep < 16; ++rep) {
        int idx = tid + rep * 256;   // = i*64 + j
        int i = idx >> 6, j = idx & 63;
        XsT[j * 68 + i] = Xp[idx];
    }
    __syncthreads();

    // pass 1: T1[i][c] = sum_j X[i][j] * Wc[j][c]
    {
        float4 a0 = {0,0,0,0}, a1 = {0,0,0,0}, a2 = {0,0,0,0}, a3 = {0,0,0,0};
        #pragma unroll 8
        for (int j = 0; j < 64; ++j) {
            float4 xv = *(const float4*)&XsT[j * 68 + g4 * 4];   // X[iq][j]
            float4 wv = *(const float4*)&Wc[j * 64 + cg * 4];    // Wc[j][cq]
            a0.x = fmaf(xv.x, wv.x, a0.x); a0.y = fmaf(xv.x, wv.y, a0.y);
            a0.z = fmaf(xv.x, wv.z, a0.z); a0.w = fmaf(xv.x, wv.w, a0.w);
            a1.x = fmaf(xv.y, wv.x, a1.x); a1.y = fmaf(xv.y, wv.y, a1.y);
            a1.z = fmaf(xv.y, wv.z, a1.z); a1.w = fmaf(xv.y, wv.w, a1.w);
            a2.x = fmaf(xv.z, wv.x, a2.x); a2.y = fmaf(xv.z, wv.y, a2.y);
            a2.z = fmaf(xv.z, wv.z, a2.z); a2.w = fmaf(xv.z, wv.w, a2.w);
            a3.x = fmaf(xv.w, wv.x, a3.x); a3.y = fmaf(xv.w, wv.y, a3.y);
            a3.z = fmaf(xv.w, wv.z, a3.z); a3.w = fmaf(xv.w, wv.w, a3.w);
        }
        *(float4*)&T1r[(g4 * 4 + 0) * 68 + cg * 4] = a0;
        *(float4*)&T1r[(g4 * 4 + 1) * 68 + cg * 4] = a1;
        *(float4*)&T1r[(g4 * 4 + 2) * 68 + cg * 4] = a2;
        *(float4*)&T1r[(g4 * 4 + 3) * 68 + cg * 4] = a3;
    }
    __syncthreads();

    // pass 2: Y[a][c] = sum_i Wr[i][a] * T1[i][c]
    {
        float4 y0 = {0,0,0,0}, y1 = {0,0,0,0}, y2 = {0,0,0,0}, y3 = {0,0,0,0};
        #pragma unroll 8
        for (int i = 0; i < 64; ++i) {
            float4 wv = *(const float4*)&Wr[i * 64 + g4 * 4];    // Wr[i][aq]
            float4 tv = *(const float4*)&T1r[i * 68 + cg * 4];   // T1[i][cq]
            y0.x = fmaf(wv.x, tv.x, y0.x); y0.y = fmaf(wv.x, tv.y, y0.y);
            y0.z = fmaf(wv.x, tv.z, y0.z); y0.w = fmaf(wv.x, tv.w, y0.w);
            y1.x = fmaf(wv.y, tv.x, y1.x); y1.y = fmaf(wv.y, tv.y, y1.y);
            y1.z = fmaf(wv.y, tv.z, y1.z); y1.w = fmaf(wv.y, tv.w, y1.w);
            y2.x = fmaf(wv.z, tv.x, y2.x); y2.y = fmaf(wv.z, tv.y, y2.y);
            y2.z = fmaf(wv.z, tv.z, y2.z); y2.w = fmaf(wv.z, tv.w, y2.w);
            y3.x = fmaf(wv.w, tv.x, y3.x); y3.y = fmaf(wv.w, tv.y, y3.y);
            y3.z = fmaf(wv.w, tv.z, y3.z); y3.w = fmaf(wv.w, tv.w, y3.w);
        }
        float4 ys[4] = {y0, y1, y2, y3};
        if (separated) {
            const int bI = token / TT, t = token % TT;
            const int r = cg >> 2, cc = (cg & 3) * 4;
            #pragma unroll
            for (int aa = 0; aa < 4; ++aa) {
                int a = g4 * 4 + aa, l = a >> 4, p = a & 15;
                float4 bv = *(const float4*)&bias[a * 64 + cg * 4];
                float4 v;
                v.x = (ys[aa].x + bv.x) * scale; v.y = (ys[aa].y + bv.y) * scale;
                v.z = (ys[aa].z + bv.z) * scale; v.w = (ys[aa].w + bv.w) * scale;
                *(float4*)&dst[(((bI * HEADS + (l * RH + r)) * TT) + t) * 256 + p * 16 + cc] = v;
            }
        } else {
            #pragma unroll
            for (int aa = 0; aa < 4; ++aa) {
                int a = g4 * 4 + aa;
                float4 bv = *(const float4*)&bias[a * 64 + cg * 4];
                float4 v;
                v.x = (ys[aa].x + bv.x) * scale; v.y = (ys[aa].y + bv.y) * scale;
                v.z = (ys[aa].z + bv.z) * scale; v.w = (ys[aa].w + bv.w) * scale;
                *(float4*)&dst[token * 4096 + a * 64 + cg * 4] = v;
            }
        }
    }
}

__global__ __launch_bounds__(256, 2) void pdense_qkv_kernel(
    const float* __restrict__ Xq, const float* __restrict__ Xk, const float* __restrict__ Xv,
    const float* __restrict__ Wq_row, const float* __restrict__ Wq_col, const float* __restrict__ bq,
    const float* __restrict__ Wk_row, const float* __restrict__ Wk_col, const float* __restrict__ bk,
    const float* __restrict__ Wv_row, const float* __restrict__ Wv_col, const float* __restrict__ bv,
    float* __restrict__ q_s, float* __restrict__ k_s, float* __restrict__ v_s)
{
    const int which = blockIdx.x / NTOK;
    const int token = blockIdx.x % NTOK;

    if (which == 0)
        pdense_body(Xq + token * 4096, Wq_row, Wq_col, bq, q_s, INV_H, 1, token);
    else if (which == 1)
        pdense_body(Xk + token * 4096, Wk_row, Wk_col, bk, k_s, INV_H, 1, token);
    else
        pdense_body(Xv + token * 4096, Wv_row, Wv_col, bv, v_s, INV_H, 1, token);
}

__global__ __launch_bounds__(256, 2) void pdense_out_kernel(
    const float* __restrict__ X, const float* __restrict__ Wr,
    const float* __restrict__ Wc, const float* __restrict__ bias,
    float* __restrict__ dst)
{
    pdense_body(X + blockIdx.x * 4096, Wr, Wc, bias, dst, INV_H, 0, blockIdx.x);
}

// ---------------------------------------------------------------------------
// Fused attention. Block = (batch, head, chunk of NQ=4 query tokens).
// K/V staged in LDS per 16-j chunk, padded [u][260] layout.
// Thread (p,u): 4 softmax rows; 8 ds_read_b128 per j serve 4 rows (~2/row).
// ---------------------------------------------------------------------------
__global__ __launch_bounds__(256, 2) void attn_kernel(
    const float* __restrict__ q_s, const float* __restrict__ k_s,
    const float* __restrict__ v_s, float* __restrict__ att)
{
    __shared__ float Ks[16 * KSTRIDE];
    __shared__ float Vs[16 * KSTRIDE];

    const int qc   = blockIdx.x % QCHUNKS;
    const int head = (blockIdx.x / QCHUNKS) % HEADS;
    const int bI   = blockIdx.x / (QCHUNKS * HEADS);
    const int l = head >> 2, r = head & 3;
    const int i0 = qc * NQ;
    const int tid = threadIdx.x;
    const int p = tid >> 4, u = tid & 15;

    if (r > l) {
        #pragma unroll
        for (int qi = 0; qi < NQ; ++qi)
            att[(((size_t)(bI * TT + i0 + qi) * DD) + (l * 16 + p)) * DD + r * 16 + u] = 0.f;
        return;
    }

    const size_t hb = (size_t)(bI * HEADS + head) * TT * 256;

    // Q rows (p,:) for NQ query tokens -> registers
    float4 q[NQ][4];
    #pragma unroll
    for (int qi = 0; qi < NQ; ++qi) {
        const float4* qp = (const float4*)(q_s + hb + (size_t)(i0 + qi) * 256 + p * 16);
        q[qi][0] = qp[0]; q[qi][1] = qp[1]; q[qi][2] = qp[2]; q[qi][3] = qp[3];
    }

    // staging indices: thread -> (sj = tid>>4, su = tid&15)
    const int su = tid & 15;
    const int sj = tid >> 4;
    float4* ksl = ((float4*)Ks) + su * KSTRIDE4 + sj * 4;
    float4* vsl = ((float4*)Vs) + su * KSTRIDE4 + sj * 4;

    float lsum[NQ];
    float acc[NQ][16];
    #pragma unroll
    for (int qi = 0; qi < NQ; ++qi) {
        lsum[qi] = 0.f;
        #pragma unroll
        for (int t = 0; t < 16; ++t) acc[qi][t] = 0.f;
    }

    const float4* kread = ((const float4*)Ks) + u * KSTRIDE4;
    const float4* vread = ((const float4*)Vs) + u * KSTRIDE4;

    for (int ch = 0; ch < NCHUNK; ++ch) {
        const int j0 = ch * JC;
        {
            const float4* gk = (const float4*)(k_s + hb + (size_t)(j0 + sj) * 256 + su * 16);
            const float4* gv = (const float4*)(v_s + hb + (size_t)(j0 + sj) * 256 + su * 16);
            float4 a0 = gk[0], a1 = gk[1], a2 = gk[2], a3 = gk[3];
            float4 b0 = gv[0], b1 = gv[1], b2 = gv[2], b3 = gv[3];
            __syncthreads();   // protect previous chunk's readers
            ksl[0] = a0; ksl[1] = a1; ksl[2] = a2; ksl[3] = a3;
            vsl[0] = b0; vsl[1] = b1; vsl[2] = b2; vsl[3] = b3;
            __syncthreads();
        }

        #pragma unroll 2
        for (int jj = 0; jj < JC; ++jj) {
            float4 k0 = kread[jj * 4 + 0], k1 = kread[jj * 4 + 1];
            float4 k2 = kread[jj * 4 + 2], k3 = kread[jj * 4 + 3];
            float4 v0 = vread[jj * 4 + 0], v1 = vread[jj * 4 + 1];
            float4 v2 = vread[jj * 4 + 2], v3 = vread[jj * 4 + 3];

            #pragma unroll
            for (int qi = 0; qi < NQ; ++qi) {
                float g0 = q[qi][0].x * k0.x;
                g0 = fmaf(q[qi][0].y, k0.y, g0);
                g0 = fmaf(q[qi][0].z, k0.z, g0);
                g0 = fmaf(q[qi][0].w, k0.w, g0);
                float g1 = q[qi][1].x * k1.x;
                g1 = fmaf(q[qi][1].y, k1.y, g1);
                g1 = fmaf(q[qi][1].z, k1.z, g1);
                g1 = fmaf(q[qi][1].w, k1.w, g1);
                float g2 = q[qi][2].x * k2.x;
                g2 = fmaf(q[qi][2].y, k2.y, g2);
                g2 = fmaf(q[qi][2].z, k2.z, g2);
                g2 = fmaf(q[qi][2].w, k2.w, g2);
                float g3 = q[qi][3].x * k3.x;
                g3 = fmaf(q[qi][3].y, k3.y, g3);
                g3 = fmaf(q[qi][3].z, k3.z, g3);
                g3 = fmaf(q[qi][3].w, k3.w, g3);
                float S = (g0 + g1) + (g2 + g3);

                float w = __expf(S * INV_H);
                lsum[qi] += w;
                acc[qi][0]  += w * v0.x;  acc[qi][1]  += w * v0.y;
                acc[qi][2]  += w * v0.z;  acc[qi][3]  += w * v0.w;
                acc[qi][4]  += w * v1.x;  acc[qi][5]  += w * v1.y;
                acc[qi][6]  += w * v1.z;  acc[qi][7]  += w * v1.w;
                acc[qi][8]  += w * v2.x;  acc[qi][9]  += w * v2.y;
                acc[qi][10] += w * v2.z;  acc[qi][11] += w * v2.w;
                acc[qi][12] += w * v3.x;  acc[qi][13] += w * v3.y;
                acc[qi][14] += w * v3.z;  acc[qi][15] += w * v3.w;
            }
        }
    }

    #pragma unroll
    for (int qi = 0; qi < NQ; ++qi) {
        float inv = 1.f / lsum[qi];
        #pragma unroll
        for (int t = 0; t < 16; ++t) acc[qi][t] *= inv;

        #pragma unroll
        for (int mask = 1; mask < 16; mask <<= 1) {
            #pragma unroll
            for (int t = 0; t < 16; ++t)
                acc[qi][t] += __shfl_xor(acc[qi][t], mask, 16);
        }

        float outv = acc[qi][0];
        #pragma unroll
        for (int t = 1; t < 16; ++t)
            outv = (u == t) ? acc[qi][t] : outv;

        att[(((size_t)(bI * TT + i0 + qi) * DD) + (l * 16 + p)) * DD + r * 16 + u] = outv;
    }
}

// ---------------------------------------------------------------------------
extern "C" void kernel_launch(void* const* d_in, const int* in_sizes, int n_in,
                              void* d_out, int out_size, void* d_ws, size_t ws_size,
                              hipStream_t stream) {
    const float* queries = (const float*)d_in[0];
    const float* keys    = (const float*)d_in[1];
    const float* values  = (const float*)d_in[2];
    const float* Wq_row  = (const float*)d_in[3];
    const float* Wq_col  = (const float*)d_in[4];
    const float* bq      = (const float*)d_in[5];
    const float* Wk_row  = (const float*)d_in[6];
    const float* Wk_col  = (const float*)d_in[7];
    const float* bk      = (const float*)d_in[8];
    const float* Wv_row  = (const float*)d_in[9];
    const float* Wv_col  = (const float*)d_in[10];
    const float* bv      = (const float*)d_in[11];
    const float* Wo_row  = (const float*)d_in[12];
    const float* Wo_col  = (const float*)d_in[13];
    const float* bo      = (const float*)d_in[14];
    float* out = (float*)d_out;

    const size_t SEP = (size_t)BB * HEADS * TT * 256;
    float* ws  = (float*)d_ws;
    float* q_s = ws;
    float* k_s = q_s + SEP;
    float* v_s = k_s + SEP;
    float* att = v_s + SEP;

    pdense_qkv_kernel<<<3 * NTOK, 256, 0, stream>>>(
        queries, keys, values,
        Wq_row, Wq_col, bq, Wk_row, Wk_col, bk, Wv_row, Wv_col, bv,
        q_s, k_s, v_s);

    attn_kernel<<<BB * HEADS * QCHUNKS, 256, 0, stream>>>(q_s, k_s, v_s, att);

    pdense_out_kernel<<<NTOK, 256, 0, stream>>>(att, Wo_row, Wo_col, bo, out);
}

// Round 7
// 83.232 us; speedup vs baseline: 2.6431x; 1.3132x over previous
//
#include <hip/hip_runtime.h>
#include <hip/hip_bf16.h>
#include <math.h>

typedef unsigned int uint32;

// Problem constants
#define LH 4
#define RH 4
#define HD 16
#define DD 64
#define BB 2
#define TT 96
#define NTOK (BB*TT)           // 192
#define HEADS (LH*RH)          // 16
#define VHEADS 10              // heads with r <= l
#define INV_H 0.0625f
#define NQ 4
#define QCHUNKS (TT/NQ)        // 24
#define JC 16                  // K/V j-chunk staged in LDS
#define NCHUNK (TT/JC)         // 6
#define KSTR4 65               // K LDS row stride per u, in float4 (260 dw)
#define VSTR8 33               // V LDS row stride per u, in uint4 (264 ushort)
#define ZBLK 48                // zerofill blocks appended to pdense_qkv

__device__ __forceinline__ unsigned short f2bf(float f) {
    __hip_bfloat16 h = __float2bfloat16(f);
    return __builtin_bit_cast(unsigned short, h);
}

// ---------------------------------------------------------------------------
// PartialDense body: Y = (Wr^T (X Wc) + b) * scale for ONE token (64x64).
// Thread (g4, cg) computes a 4x4 tile/pass: 16 FMA per LDS float4 + global float4.
// MODE: 0 = fp32 merged, 1 = fp32 separated, 2 = bf16 separated
// ---------------------------------------------------------------------------
template<int MODE>
__device__ __forceinline__ void pdense_body(
    const float* __restrict__ Xp,
    const float* __restrict__ Wr, const float* __restrict__ Wc,
    const float* __restrict__ bias, void* __restrict__ dstv,
    float scale, int token)
{
    __shared__ float XsT[64 * 68];   // X transposed: XsT[j*68 + i]
    __shared__ float T1r[64 * 68];   // T1 row-major: T1r[i*68 + c]

    const int tid = threadIdx.x;
    const int g4 = tid >> 4;         // 0..15 (i/a quad)
    const int cg = tid & 15;         // 0..15 (c quad)

    #pragma unroll
    for (int rep = 0; rep < 16; ++rep) {
        int idx = tid + rep * 256;   // = i*64 + j
        int i = idx >> 6, j = idx & 63;
        XsT[j * 68 + i] = Xp[idx];
    }
    __syncthreads();

    // pass 1: T1[i][c] = sum_j X[i][j] * Wc[j][c]
    {
        float4 a0 = {0,0,0,0}, a1 = {0,0,0,0}, a2 = {0,0,0,0}, a3 = {0,0,0,0};
        #pragma unroll 8
        for (int j = 0; j < 64; ++j) {
            float4 xv = *(const float4*)&XsT[j * 68 + g4 * 4];
            float4 wv = *(const float4*)&Wc[j * 64 + cg * 4];
            a0.x = fmaf(xv.x, wv.x, a0.x); a0.y = fmaf(xv.x, wv.y, a0.y);
            a0.z = fmaf(xv.x, wv.z, a0.z); a0.w = fmaf(xv.x, wv.w, a0.w);
            a1.x = fmaf(xv.y, wv.x, a1.x); a1.y = fmaf(xv.y, wv.y, a1.y);
            a1.z = fmaf(xv.y, wv.z, a1.z); a1.w = fmaf(xv.y, wv.w, a1.w);
            a2.x = fmaf(xv.z, wv.x, a2.x); a2.y = fmaf(xv.z, wv.y, a2.y);
            a2.z = fmaf(xv.z, wv.z, a2.z); a2.w = fmaf(xv.z, wv.w, a2.w);
            a3.x = fmaf(xv.w, wv.x, a3.x); a3.y = fmaf(xv.w, wv.y, a3.y);
            a3.z = fmaf(xv.w, wv.z, a3.z); a3.w = fmaf(xv.w, wv.w, a3.w);
        }
        *(float4*)&T1r[(g4 * 4 + 0) * 68 + cg * 4] = a0;
        *(float4*)&T1r[(g4 * 4 + 1) * 68 + cg * 4] = a1;
        *(float4*)&T1r[(g4 * 4 + 2) * 68 + cg * 4] = a2;
        *(float4*)&T1r[(g4 * 4 + 3) * 68 + cg * 4] = a3;
    }
    __syncthreads();

    // pass 2: Y[a][c] = sum_i Wr[i][a] * T1[i][c]
    {
        float4 y0 = {0,0,0,0}, y1 = {0,0,0,0}, y2 = {0,0,0,0}, y3 = {0,0,0,0};
        #pragma unroll 8
        for (int i = 0; i < 64; ++i) {
            float4 wv = *(const float4*)&Wr[i * 64 + g4 * 4];
            float4 tv = *(const float4*)&T1r[i * 68 + cg * 4];
            y0.x = fmaf(wv.x, tv.x, y0.x); y0.y = fmaf(wv.x, tv.y, y0.y);
            y0.z = fmaf(wv.x, tv.z, y0.z); y0.w = fmaf(wv.x, tv.w, y0.w);
            y1.x = fmaf(wv.y, tv.x, y1.x); y1.y = fmaf(wv.y, tv.y, y1.y);
            y1.z = fmaf(wv.y, tv.z, y1.z); y1.w = fmaf(wv.y, tv.w, y1.w);
            y2.x = fmaf(wv.z, tv.x, y2.x); y2.y = fmaf(wv.z, tv.y, y2.y);
            y2.z = fmaf(wv.z, tv.z, y2.z); y2.w = fmaf(wv.z, tv.w, y2.w);
            y3.x = fmaf(wv.w, tv.x, y3.x); y3.y = fmaf(wv.w, tv.y, y3.y);
            y3.z = fmaf(wv.w, tv.z, y3.z); y3.w = fmaf(wv.w, tv.w, y3.w);
        }
        float4 ys[4] = {y0, y1, y2, y3};
        const int bI = token / TT, t = token % TT;
        const int r = cg >> 2, cc = (cg & 3) * 4;
        #pragma unroll
        for (int aa = 0; aa < 4; ++aa) {
            int a = g4 * 4 + aa;
            float4 bv = *(const float4*)&bias[a * 64 + cg * 4];
            float4 v;
            v.x = (ys[aa].x + bv.x) * scale; v.y = (ys[aa].y + bv.y) * scale;
            v.z = (ys[aa].z + bv.z) * scale; v.w = (ys[aa].w + bv.w) * scale;
            if (MODE == 0) {
                *(float4*)((float*)dstv + token * 4096 + a * 64 + cg * 4) = v;
            } else {
                int lh = a >> 4, p = a & 15;
                size_t off = (size_t)(((bI * HEADS + (lh * RH + r)) * TT) + t) * 256 + p * 16 + cc;
                if (MODE == 1) {
                    *(float4*)((float*)dstv + off) = v;
                } else {
                    uint2 pk;
                    pk.x = (uint32)f2bf(v.x) | ((uint32)f2bf(v.y) << 16);
                    pk.y = (uint32)f2bf(v.z) | ((uint32)f2bf(v.w) << 16);
                    *(uint2*)((unsigned short*)dstv + off) = pk;
                }
            }
        }
    }
}

// Fused q/k/v projection + att zerofill tail blocks
__global__ __launch_bounds__(256, 2) void pdense_qkv_kernel(
    const float* __restrict__ Xq, const float* __restrict__ Xk, const float* __restrict__ Xv,
    const float* __restrict__ Wq_row, const float* __restrict__ Wq_col, const float* __restrict__ bq,
    const float* __restrict__ Wk_row, const float* __restrict__ Wk_col, const float* __restrict__ bk,
    const float* __restrict__ Wv_row, const float* __restrict__ Wv_col, const float* __restrict__ bv,
    float* __restrict__ q_s, float* __restrict__ k_s, unsigned short* __restrict__ v_s,
    float* __restrict__ att)
{
    const int bid = blockIdx.x;
    if (bid >= 3 * NTOK) {
        // zero the att buffer (covers r>l masked head blocks)
        const int zb = bid - 3 * NTOK;
        float4* a4 = (float4*)att;
        #pragma unroll
        for (int k = 0; k < 16; ++k)
            a4[zb * 4096 + k * 256 + threadIdx.x] = float4{0.f, 0.f, 0.f, 0.f};
        return;
    }
    const int which = bid / NTOK;
    const int token = bid % NTOK;

    if (which == 0)
        pdense_body<1>(Xq + token * 4096, Wq_row, Wq_col, bq, q_s, INV_H, token);
    else if (which == 1)
        pdense_body<1>(Xk + token * 4096, Wk_row, Wk_col, bk, k_s, INV_H, token);
    else
        pdense_body<2>(Xv + token * 4096, Wv_row, Wv_col, bv, v_s, INV_H, token);
}

__global__ __launch_bounds__(256, 2) void pdense_out_kernel(
    const float* __restrict__ X, const float* __restrict__ Wr,
    const float* __restrict__ Wc, const float* __restrict__ bias,
    float* __restrict__ dst)
{
    pdense_body<0>(X + blockIdx.x * 4096, Wr, Wc, bias, dst, INV_H, blockIdx.x);
}

// ---------------------------------------------------------------------------
// Fused attention. Block = (batch, VALID head, chunk of NQ=4 queries).
// K fp32 + V bf16 staged in LDS per 16-j chunk. Q pinned in VGPRs (scalar asm).
// Final cross-u sum via reduce-scatter butterfly (15 shfl/row, not 64).
// ---------------------------------------------------------------------------
__global__ __launch_bounds__(256, 2) void attn_kernel(
    const float* __restrict__ q_s, const float* __restrict__ k_s,
    const unsigned short* __restrict__ v_s, float* __restrict__ att)
{
    __shared__ float  Ks[16 * KSTR4 * 4];         // [u][j*16 + f] fp32, pad 4 dw
    __shared__ unsigned short Vs[16 * VSTR8 * 8]; // [u][j*16 + f] bf16, pad 8 hw

    const int qc = blockIdx.x % QCHUNKS;
    const int vh = (blockIdx.x / QCHUNKS) % VHEADS;
    const int bI = blockIdx.x / (QCHUNKS * VHEADS);
    const int l = (vh >= 1) + (vh >= 3) + (vh >= 6);
    const int r = vh - (l * (l + 1)) / 2;
    const int head = l * RH + r;
    const int i0 = qc * NQ;
    const int tid = threadIdx.x;
    const int p = tid >> 4, u = tid & 15;

    const size_t hb = (size_t)(bI * HEADS + head) * TT * 256;

    // Q rows -> registers, pre-scaled by 1/h, pinned scalar-wise (compiles to nothing)
    float q[NQ][16];
    #pragma unroll
    for (int qi = 0; qi < NQ; ++qi) {
        const float4* qp = (const float4*)(q_s + hb + (size_t)(i0 + qi) * 256 + p * 16);
        #pragma unroll
        for (int kk = 0; kk < 4; ++kk) {
            float4 t = qp[kk];
            q[qi][kk * 4 + 0] = t.x * INV_H;
            q[qi][kk * 4 + 1] = t.y * INV_H;
            q[qi][kk * 4 + 2] = t.z * INV_H;
            q[qi][kk * 4 + 3] = t.w * INV_H;
        }
    }
    #pragma unroll
    for (int qi = 0; qi < NQ; ++qi)
        #pragma unroll
        for (int kk = 0; kk < 16; ++kk)
            asm volatile("" : "+v"(q[qi][kk]));

    // staging indices
    const int su = tid & 15;
    const int sj = tid >> 4;
    float4* kwr = ((float4*)Ks) + su * KSTR4 + sj * 4;
    uint4*  vwr = ((uint4*)Vs) + su * VSTR8 + sj * 2;

    float lsum[NQ];
    float acc[NQ][16];
    #pragma unroll
    for (int qi = 0; qi < NQ; ++qi) {
        lsum[qi] = 0.f;
        #pragma unroll
        for (int t = 0; t < 16; ++t) acc[qi][t] = 0.f;
    }

    const float4* kread = ((const float4*)Ks) + u * KSTR4;
    const uint4*  vread = ((const uint4*)Vs) + u * VSTR8;

    for (int ch = 0; ch < NCHUNK; ++ch) {
        const int j0 = ch * JC;
        {
            const float4* gk = (const float4*)(k_s + hb + (size_t)(j0 + sj) * 256 + su * 16);
            const uint4*  gv = (const uint4*)(v_s + hb + (size_t)(j0 + sj) * 256 + su * 16);
            float4 a0 = gk[0], a1 = gk[1], a2 = gk[2], a3 = gk[3];
            uint4 b0 = gv[0], b1 = gv[1];
            __syncthreads();   // protect previous chunk's readers
            kwr[0] = a0; kwr[1] = a1; kwr[2] = a2; kwr[3] = a3;
            vwr[0] = b0; vwr[1] = b1;
            __syncthreads();
        }

        #pragma unroll 2
        for (int jj = 0; jj < JC; ++jj) {
            float4 k0 = kread[jj * 4 + 0], k1 = kread[jj * 4 + 1];
            float4 k2 = kread[jj * 4 + 2], k3 = kread[jj * 4 + 3];
            uint4 r0 = vread[jj * 2 + 0], r1 = vread[jj * 2 + 1];
            float vv[16];
            vv[0]  = __uint_as_float(r0.x << 16);
            vv[1]  = __uint_as_float(r0.x & 0xffff0000u);
            vv[2]  = __uint_as_float(r0.y << 16);
            vv[3]  = __uint_as_float(r0.y & 0xffff0000u);
            vv[4]  = __uint_as_float(r0.z << 16);
            vv[5]  = __uint_as_float(r0.z & 0xffff0000u);
            vv[6]  = __uint_as_float(r0.w << 16);
            vv[7]  = __uint_as_float(r0.w & 0xffff0000u);
            vv[8]  = __uint_as_float(r1.x << 16);
            vv[9]  = __uint_as_float(r1.x & 0xffff0000u);
            vv[10] = __uint_as_float(r1.y << 16);
            vv[11] = __uint_as_float(r1.y & 0xffff0000u);
            vv[12] = __uint_as_float(r1.z << 16);
            vv[13] = __uint_as_float(r1.z & 0xffff0000u);
            vv[14] = __uint_as_float(r1.w << 16);
            vv[15] = __uint_as_float(r1.w & 0xffff0000u);

            #pragma unroll
            for (int qi = 0; qi < NQ; ++qi) {
                float g0 = q[qi][0] * k0.x;
                g0 = fmaf(q[qi][1], k0.y, g0);
                g0 = fmaf(q[qi][2], k0.z, g0);
                g0 = fmaf(q[qi][3], k0.w, g0);
                float g1 = q[qi][4] * k1.x;
                g1 = fmaf(q[qi][5], k1.y, g1);
                g1 = fmaf(q[qi][6], k1.z, g1);
                g1 = fmaf(q[qi][7], k1.w, g1);
                float g2 = q[qi][8] * k2.x;
                g2 = fmaf(q[qi][9], k2.y, g2);
                g2 = fmaf(q[qi][10], k2.z, g2);
                g2 = fmaf(q[qi][11], k2.w, g2);
                float g3 = q[qi][12] * k3.x;
                g3 = fmaf(q[qi][13], k3.y, g3);
                g3 = fmaf(q[qi][14], k3.z, g3);
                g3 = fmaf(q[qi][15], k3.w, g3);
                float S = (g0 + g1) + (g2 + g3);

                float w = __expf(S);       // 1/h folded into q
                lsum[qi] += w;
                #pragma unroll
                for (int t = 0; t < 16; ++t)
                    acc[qi][t] = fmaf(w, vv[t], acc[qi][t]);
            }
        }
    }

    // normalize + reduce-scatter over u: lane u ends with output column u
    #pragma unroll
    for (int qi = 0; qi < NQ; ++qi) {
        float inv = 1.f / lsum[qi];
        float cur[16];
        #pragma unroll
        for (int t = 0; t < 16; ++t) cur[t] = acc[qi][t] * inv;

        #pragma unroll
        for (int s = 0; s < 8; ++s) {
            float send = (u & 8) ? cur[s] : cur[s + 8];
            float keep = (u & 8) ? cur[s + 8] : cur[s];
            cur[s] = keep + __shfl_xor(send, 8, 16);
        }
        #pragma unroll
        for (int s = 0; s < 4; ++s) {
            float send = (u & 4) ? cur[s] : cur[s + 4];
            float keep = (u & 4) ? cur[s + 4] : cur[s];
            cur[s] = keep + __shfl_xor(send, 4, 16);
        }
        #pragma unroll
        for (int s = 0; s < 2; ++s) {
            float send = (u & 2) ? cur[s] : cur[s + 2];
            float keep = (u & 2) ? cur[s + 2] : cur[s];
            cur[s] = keep + __shfl_xor(send, 2, 16);
        }
        {
            float send = (u & 1) ? cur[0] : cur[1];
            float keep = (u & 1) ? cur[1] : cur[0];
            cur[0] = keep + __shfl_xor(send, 1, 16);
        }

        att[(((size_t)(bI * TT + i0 + qi) * DD) + (l * 16 + p)) * DD + r * 16 + u] = cur[0];
    }
}

// ---------------------------------------------------------------------------
extern "C" void kernel_launch(void* const* d_in, const int* in_sizes, int n_in,
                              void* d_out, int out_size, void* d_ws, size_t ws_size,
                              hipStream_t stream) {
    const float* queries = (const float*)d_in[0];
    const float* keys    = (const float*)d_in[1];
    const float* values  = (const float*)d_in[2];
    const float* Wq_row  = (const float*)d_in[3];
    const float* Wq_col  = (const float*)d_in[4];
    const float* bq      = (const float*)d_in[5];
    const float* Wk_row  = (const float*)d_in[6];
    const float* Wk_col  = (const float*)d_in[7];
    const float* bk      = (const float*)d_in[8];
    const float* Wv_row  = (const float*)d_in[9];
    const float* Wv_col  = (const float*)d_in[10];
    const float* bv      = (const float*)d_in[11];
    const float* Wo_row  = (const float*)d_in[12];
    const float* Wo_col  = (const float*)d_in[13];
    const float* bo      = (const float*)d_in[14];
    float* out = (float*)d_out;

    const size_t SEP = (size_t)BB * HEADS * TT * 256;   // 786432 elements
    float* ws  = (float*)d_ws;
    float* q_s = ws;
    float* k_s = ws + SEP;
    unsigned short* v_s = (unsigned short*)(ws + 2 * SEP);
    float* att = ws + 2 * SEP + SEP / 2;

    pdense_qkv_kernel<<<3 * NTOK + ZBLK, 256, 0, stream>>>(
        queries, keys, values,
        Wq_row, Wq_col, bq, Wk_row, Wk_col, bk, Wv_row, Wv_col, bv,
        q_s, k_s, v_s, att);

    attn_kernel<<<BB * VHEADS * QCHUNKS, 256, 0, stream>>>(q_s, k_s, v_s, att);

    pdense_out_kernel<<<NTOK, 256, 0, stream>>>(att, Wo_row, Wo_col, bo, out);
}